// Round 7
// baseline (241.840 us; speedup 1.0000x reference)
//
#include <hip/hip_runtime.h>
#include <hip/hip_fp16.h>
#include <cstddef>
#include <cstdint>

#define DIM 128
#define SEQ 2048
#define NB 32
#define NCH 512
#define NROWS (NB * SEQ)          // 65536

typedef _Float16 half8 __attribute__((ext_vector_type(8)));
typedef float    f32x4 __attribute__((ext_vector_type(4)));

// ws layout: cmb fp16 [NROWS][NCH] | Wfg fp16 frag-linear [65536]
#define CMB_BYTES ((size_t)NROWS * NCH * 2)       // 67,108,864
#define WFG_OFF   CMB_BYTES
#define WFG_BYTES ((size_t)NCH * DIM * 2)         // 131,072
#define WS_NEEDED (WFG_OFF + WFG_BYTES)           // ~64.1 MB (proven available)

__device__ __forceinline__ float sigf(float v) {
    return 1.0f / (1.0f + __expf(-v));
}

// ---------------------------------------------------------------------------
// k0: Wfg = Wf (fp16) pre-swizzled into MFMA B-fragment linear layout.
// ---------------------------------------------------------------------------
__global__ void k0_wfg(const float* __restrict__ Wf, _Float16* __restrict__ Wfg) {
    int t = blockIdx.x * 256 + threadIdx.x;       // 8192 threads x 8 elems
#pragma unroll
    for (int i = 0; i < 8; ++i) {
        int o = t * 8 + i;                         // 65536 total
        int j    = o & 7;
        int lane = (o >> 3) & 63;
        int q    = lane >> 4, n16 = lane & 15;
        int ct   = (o >> 9) & 7;
        int ks   = (o >> 12) & 1;
        int kb   = o >> 13;
        int k = kb * 64 + ks * 32 + q * 8 + j;
        int n = ct * 16 + n16;
        Wfg[o] = (_Float16)Wf[n * NCH + k];
    }
}

// ---------------------------------------------------------------------------
// kfused v6: block = (batch b, 16-channel group) -> grid 32x32 = 1024 blocks
//   (4 blocks/CU). Thread owns 1 channel x 4 contiguous s. A-frags read
//   DIRECTLY from fp32 x (8 float4 prefetch regs, inline cvt to fp16);
//   B-frags in LDS (8 KB, staged once). 2 barriers/tile.
// ---------------------------------------------------------------------------
__global__ __launch_bounds__(256, 4) void kfused(
        const float* __restrict__ x,
        const float* __restrict__ Wa_u, const float* __restrict__ ba_u,
        const float* __restrict__ Wi_u, const float* __restrict__ bi_u,
        const float* __restrict__ g_u,
        const float* __restrict__ Wa_w, const float* __restrict__ ba_w,
        const float* __restrict__ Wi_w, const float* __restrict__ bi_w,
        const float* __restrict__ g_w,
        _Float16* __restrict__ cmb) {
    __shared__ _Float16 Bs[4096];        // [ks(4)][nt(2)][lane(64)][8] = 8 KB
    __shared__ float2   seg[16][17];
    __shared__ float    pref[16][17];
    __shared__ float    carry[16];

    const int tid  = threadIdx.x;
    const int lane = tid & 63;
    const int w    = tid >> 6;
    const int quad = lane >> 4;
    const int n16  = lane & 15;

    const int b  = blockIdx.x;           // 0..31
    const int cg = blockIdx.y;           // 0..31
    const int p  = cg >> 4;              // path
    const int ebase = (cg & 15) * 16;    // 16 channels per block

    const float* Wa  = p ? Wa_w : Wa_u;
    const float* Wi  = p ? Wi_w : Wi_u;
    const float* bap = p ? ba_w : ba_u;
    const float* bip = p ? bi_w : bi_u;
    const float* gp  = p ? g_w  : g_u;

    // ---- stage Bs once: slot sl = ks*128 + nt*64 + l  (512 slots, 2/thread)
    for (int sl = tid; sl < 512; sl += 256) {
        int l  = sl & 63;
        int nt = (sl >> 6) & 1;          // 0 = pa (Wa), 1 = pi (Wi)
        int ks = sl >> 7;
        int qq = l >> 4, nn = l & 15;
        int e = ebase + nn;
        const float* Wp = nt ? Wi : Wa;
        const float* src = Wp + (size_t)e * DIM + ks * 32 + qq * 8;
        float4 v0 = *(const float4*)src;
        float4 v1 = *(const float4*)(src + 4);
        half8 hv;
        hv[0] = (_Float16)v0.x; hv[1] = (_Float16)v0.y;
        hv[2] = (_Float16)v0.z; hv[3] = (_Float16)v0.w;
        hv[4] = (_Float16)v1.x; hv[5] = (_Float16)v1.y;
        hv[6] = (_Float16)v1.z; hv[7] = (_Float16)v1.w;
        *(half8*)&Bs[sl * 8] = hv;
    }

    // per-thread channel params (channel cc = n16)
    const int e = ebase + n16;
    const float rba = bap[e];
    const float rbi = bip[e];
    const float ral = sigf(gp[e]);
    if (tid < 16) carry[tid] = 0.0f;

    // incremental recency weight: sc(s) = exp(3s/2047)
    float scb = __expf((float)(w * 16 + quad * 4) * (3.0f / 2047.0f));
    const float r1   = __expf(3.0f / 2047.0f);
    const float r2   = r1 * r1;
    const float r3   = r2 * r1;
    const float cs64 = __expf(64.0f * 3.0f / 2047.0f);

    // this thread's A-fragment row in x: s_local = w*16 + n16 (= MFMA m)
    const float* xbase = x + ((size_t)b * SEQ + (size_t)(w * 16 + n16)) * DIM + quad * 8;
    _Float16* cmbb = cmb + (size_t)b * SEQ * NCH + cg * 16 + n16;

    __syncthreads();

    // preload tile 0's A data (fp32): xf[2ks] = k ks*32+quad*8..+3, xf[2ks+1] = +4..+7
    float4 xf[8];
#pragma unroll
    for (int ks = 0; ks < 4; ++ks) {
        xf[2 * ks]     = *(const float4*)(xbase + ks * 32);
        xf[2 * ks + 1] = *(const float4*)(xbase + ks * 32 + 4);
    }

    for (int t = 0; t < 32; ++t) {
        const int s0 = t * 64;

        // ---- convert prefetched fp32 -> fp16 A-frags ----
        half8 af[4];
#pragma unroll
        for (int ks = 0; ks < 4; ++ks) {
            float4 v0 = xf[2 * ks], v1 = xf[2 * ks + 1];
            half8 hv;
            hv[0] = (_Float16)v0.x; hv[1] = (_Float16)v0.y;
            hv[2] = (_Float16)v0.z; hv[3] = (_Float16)v0.w;
            hv[4] = (_Float16)v1.x; hv[5] = (_Float16)v1.y;
            hv[6] = (_Float16)v1.z; hv[7] = (_Float16)v1.w;
            af[ks] = hv;
        }

        // ---- MFMA: C[s = w*16+quad*4+reg][nt], K=128 ----
        f32x4 acc[2];
        acc[0] = (f32x4){0.f, 0.f, 0.f, 0.f};
        acc[1] = (f32x4){0.f, 0.f, 0.f, 0.f};
#pragma unroll
        for (int ks = 0; ks < 4; ++ks) {
            half8 a = af[ks];
            half8 b0 = *(const half8*)&Bs[(ks * 128 + lane) * 8];
            half8 b1 = *(const half8*)&Bs[(ks * 128 + 64 + lane) * 8];
            acc[0] = __builtin_amdgcn_mfma_f32_16x16x32_f16(a, b0, acc[0], 0, 0, 0);
            acc[1] = __builtin_amdgcn_mfma_f32_16x16x32_f16(a, b1, acc[1], 0, 0, 0);
        }

        // ---- prefetch next tile's A data (wraps at t=31; harmless) ----
        {
            int tn = (t + 1) & 31;
            const float* ab = xbase + (size_t)tn * 64 * DIM;
#pragma unroll
            for (int ks = 0; ks < 4; ++ks) {
                xf[2 * ks]     = *(const float4*)(ab + ks * 32);
                xf[2 * ks + 1] = *(const float4*)(ab + ks * 32 + 4);
            }
        }

        // ---- gates + 4-step affine compose ----
        float sc[4];
        if (p) { sc[0] = scb; sc[1] = scb * r1; sc[2] = scb * r2; sc[3] = scb * r3; }
        else   { sc[0] = sc[1] = sc[2] = sc[3] = 1.0f; }
        scb *= cs64;

        float a_s[4], u_s[4];
        float A4 = 1.0f, U4 = 0.0f;
#pragma unroll
        for (int reg = 0; reg < 4; ++reg) {
            float pa = fmaf(acc[0][reg], sc[reg], rba);
            float pi = fmaf(acc[1][reg], sc[reg], rbi);
            float rst = sigf(pa);
            float ig  = sigf(pi);
            float a   = ral * exp2f(-rst * 1.5849625007211562f);  // alpha*3^-rst
            float u   = sqrtf(fmaxf(1.0f - a * a, 0.0f)) * ig * pi;
            a_s[reg] = a; u_s[reg] = u;
            A4 *= a;
            U4 = fmaf(a, U4, u);
        }
        seg[w * 4 + quad][n16] = make_float2(A4, U4);
        __syncthreads();

        // ---- serial inter-segment scan (16 segments, lane = channel) ----
        if (tid < 16) {
            float H = carry[tid];
#pragma unroll
            for (int ts = 0; ts < 16; ++ts) {
                float2 AU = seg[ts][tid];
                pref[ts][tid] = H;
                H = fmaf(AU.x, H, AU.y);
            }
            carry[tid] = H;
        }
        __syncthreads();

        // ---- replay + direct store (2B/lane, 16-lane = 32B segments) ----
        {
            float h = pref[w * 4 + quad][n16];
            _Float16* dst = cmbb + (size_t)(s0 + w * 16 + quad * 4) * NCH;
#pragma unroll
            for (int reg = 0; reg < 4; ++reg) {
                h = fmaf(a_s[reg], h, u_s[reg]);
                dst[(size_t)reg * NCH] = (_Float16)h;
            }
        }
    }
}

// ---------------------------------------------------------------------------
// k3: round-3 structure VERBATIM (measured ~40 µs): 128-row tile, 64-wide K
//     pages, 32 MFMA/barrier, grid 512 = 2 blocks/CU.
// ---------------------------------------------------------------------------
__global__ __launch_bounds__(256, 2) void k3_mfma(
        const _Float16* __restrict__ cmb, const _Float16* __restrict__ Wfg,
        const float* __restrict__ bfv, float* __restrict__ out) {
    __shared__ _Float16 As[16 * 512];
    __shared__ _Float16 Bs[16 * 512];

    const int tid  = threadIdx.x;
    const int lane = tid & 63;
    const int w    = tid >> 6;
    const int row0 = blockIdx.x * 128;
    const int q    = lane >> 4;
    const int nn   = lane & 15;

    f32x4 acc[2][8];
#pragma unroll
    for (int rt = 0; rt < 2; ++rt)
#pragma unroll
        for (int ct = 0; ct < 8; ++ct)
            acc[rt][ct] = (f32x4){0.0f, 0.0f, 0.0f, 0.0f};

    for (int kb = 0; kb < 8; ++kb) {
        const int kc = kb * 64;
#pragma unroll
        for (int i = 0; i < 4; ++i) {
            int f = tid + i * 256;
            int r = f >> 3, k8 = f & 7;
            uint4 v = *(const uint4*)(cmb + (size_t)(row0 + r) * NCH + kc + k8 * 8);
            int rt = r >> 4, m = r & 15, ks = k8 >> 2, qq = k8 & 3;
            *(uint4*)&As[(((rt * 2 + ks) * 64) + qq * 16 + m) * 8] = v;
        }
#pragma unroll
        for (int i = 0; i < 4; ++i) {
            int f = tid + i * 256;
            uint4 v = *(const uint4*)(Wfg + (size_t)kb * 8192 + (size_t)f * 8);
            *(uint4*)&Bs[(size_t)f * 8] = v;
        }
        __syncthreads();

#pragma unroll
        for (int ks = 0; ks < 2; ++ks) {
            half8 a0 = *(const half8*)&As[(((w * 2 + 0) * 2 + ks) * 512) + lane * 8];
            half8 a1 = *(const half8*)&As[(((w * 2 + 1) * 2 + ks) * 512) + lane * 8];
#pragma unroll
            for (int ct = 0; ct < 8; ++ct) {
                half8 bb = *(const half8*)&Bs[((ks * 8 + ct) * 512) + lane * 8];
                acc[0][ct] = __builtin_amdgcn_mfma_f32_16x16x32_f16(a0, bb, acc[0][ct], 0, 0, 0);
                acc[1][ct] = __builtin_amdgcn_mfma_f32_16x16x32_f16(a1, bb, acc[1][ct], 0, 0, 0);
            }
        }
        __syncthreads();
    }

#pragma unroll
    for (int rt = 0; rt < 2; ++rt) {
        int rbase = row0 + w * 32 + rt * 16 + q * 4;
#pragma unroll
        for (int ct = 0; ct < 8; ++ct) {
            int col = ct * 16 + nn;
            float bias = bfv[col];
#pragma unroll
            for (int reg = 0; reg < 4; ++reg)
                out[(size_t)(rbase + reg) * DIM + col] = acc[rt][ct][reg] + bias;
        }
    }
}

// ---------------------------------------------------------------------------
extern "C" void kernel_launch(void* const* d_in, const int* in_sizes, int n_in,
                              void* d_out, int out_size, void* d_ws, size_t ws_size,
                              hipStream_t stream) {
    if (ws_size < WS_NEEDED) return;

    const float* x    = (const float*)d_in[0];
    const float* Wa_u = (const float*)d_in[1];
    const float* ba_u = (const float*)d_in[2];
    const float* Wi_u = (const float*)d_in[3];
    const float* bi_u = (const float*)d_in[4];
    const float* g_u  = (const float*)d_in[5];
    const float* Wa_w = (const float*)d_in[6];
    const float* ba_w = (const float*)d_in[7];
    const float* Wi_w = (const float*)d_in[8];
    const float* bi_w = (const float*)d_in[9];
    const float* g_w  = (const float*)d_in[10];
    const float* Wf   = (const float*)d_in[11];
    const float* bfv  = (const float*)d_in[12];
    float* out = (float*)d_out;

    char* ws = (char*)d_ws;
    _Float16* cmb = (_Float16*)ws;
    _Float16* Wfg = (_Float16*)(ws + WFG_OFF);

    hipLaunchKernelGGL(k0_wfg, dim3(32), dim3(256), 0, stream, Wf, Wfg);
    hipLaunchKernelGGL(kfused, dim3(32, 32), dim3(256), 0, stream,
                       x, Wa_u, ba_u, Wi_u, bi_u, g_u,
                       Wa_w, ba_w, Wi_w, bi_w, g_w, cmb);
    hipLaunchKernelGGL(k3_mfma, dim3(512), dim3(256), 0, stream,
                       cmb, Wfg, bfv, out);
}

// Round 8
// 204.940 us; speedup vs baseline: 1.1801x; 1.1801x over previous
//
#include <hip/hip_runtime.h>
#include <hip/hip_fp16.h>
#include <cstddef>
#include <cstdint>

#define DIM 128
#define SEQ 2048
#define NB 32
#define NCH 512
#define NROWS (NB * SEQ)          // 65536

typedef _Float16 half8 __attribute__((ext_vector_type(8)));
typedef float    f32x4 __attribute__((ext_vector_type(4)));

// ws layout: cmb fp16 [NROWS][NCH] | Wfg fp16 frag-linear [65536]
#define CMB_BYTES ((size_t)NROWS * NCH * 2)       // 67,108,864
#define WFG_OFF   CMB_BYTES
#define WFG_BYTES ((size_t)NCH * DIM * 2)         // 131,072
#define WS_NEEDED (WFG_OFF + WFG_BYTES)           // ~64.1 MB (proven available)

__device__ __forceinline__ float sigf(float v) {
    return 1.0f / (1.0f + __expf(-v));
}

// ---------------------------------------------------------------------------
// k0: Wfg = Wf (fp16) pre-swizzled into MFMA B-fragment linear layout.
// ---------------------------------------------------------------------------
__global__ void k0_wfg(const float* __restrict__ Wf, _Float16* __restrict__ Wfg) {
    int t = blockIdx.x * 256 + threadIdx.x;       // 8192 threads x 8 elems
#pragma unroll
    for (int i = 0; i < 8; ++i) {
        int o = t * 8 + i;                         // 65536 total
        int j    = o & 7;
        int lane = (o >> 3) & 63;
        int q    = lane >> 4, n16 = lane & 15;
        int ct   = (o >> 9) & 7;
        int ks   = (o >> 12) & 1;
        int kb   = o >> 13;
        int k = kb * 64 + ks * 32 + q * 8 + j;
        int n = ct * 16 + n16;
        Wfg[o] = (_Float16)Wf[n * NCH + k];
    }
}

// ---------------------------------------------------------------------------
// kfused v7: block = (batch b, 32-channel group), 512 threads (8 waves).
//   Grid 32x16 = 512 blocks = 2 blocks/CU x 8 waves = 4 waves/SIMD.
//   s-tiles of 128 (wave w owns m-tile w). Thread owns 2 channels x 4 s.
//   A-frags direct from fp32 x (re-read factor 16 -> ~2.1 GB L2 traffic);
//   B-frags in LDS (16 KB, staged once). 2 barriers per 128-s tile.
// ---------------------------------------------------------------------------
__global__ __launch_bounds__(512, 4) void kfused(
        const float* __restrict__ x,
        const float* __restrict__ Wa_u, const float* __restrict__ ba_u,
        const float* __restrict__ Wi_u, const float* __restrict__ bi_u,
        const float* __restrict__ g_u,
        const float* __restrict__ Wa_w, const float* __restrict__ ba_w,
        const float* __restrict__ Wi_w, const float* __restrict__ bi_w,
        const float* __restrict__ g_w,
        _Float16* __restrict__ cmb) {
    __shared__ _Float16 Bs[8192];        // [ks(4)][nt(4)][lane(64)][8] = 16 KB
    __shared__ float2   seg[32][33];     // (A,U) per (segment, channel)
    __shared__ float    pref[32][33];    // incoming h per (segment, channel)
    __shared__ float    carry[32];

    const int tid  = threadIdx.x;
    const int lane = tid & 63;
    const int w    = tid >> 6;           // wave 0..7 = m-tile (16 s each)
    const int quad = lane >> 4;
    const int n16  = lane & 15;

    const int b  = blockIdx.x;           // 0..31
    const int cg = blockIdx.y;           // 0..15
    const int p  = cg >> 3;              // path
    const int ebase = (cg & 7) * 32;     // 32 channels per block

    const float* Wa  = p ? Wa_w : Wa_u;
    const float* Wi  = p ? Wi_w : Wi_u;
    const float* bap = p ? ba_w : ba_u;
    const float* bip = p ? bi_w : bi_u;
    const float* gp  = p ? g_w  : g_u;

    // ---- stage Bs once: slot sl = ks*256 + nt*64 + l (1024 slots, 2/thread)
    //  nt: 0,1 = pa (Wa) ch 0..15 / 16..31; 2,3 = pi (Wi) same split.
    for (int sl = tid; sl < 1024; sl += 512) {
        int l  = sl & 63;
        int nt = (sl >> 6) & 3;
        int ks = sl >> 8;
        int qq = l >> 4, nn = l & 15;
        int e = ebase + (nt & 1) * 16 + nn;
        const float* Wp = (nt >> 1) ? Wi : Wa;
        const float* src = Wp + (size_t)e * DIM + ks * 32 + qq * 8;
        float4 v0 = *(const float4*)src;
        float4 v1 = *(const float4*)(src + 4);
        half8 hv;
        hv[0] = (_Float16)v0.x; hv[1] = (_Float16)v0.y;
        hv[2] = (_Float16)v0.z; hv[3] = (_Float16)v0.w;
        hv[4] = (_Float16)v1.x; hv[5] = (_Float16)v1.y;
        hv[6] = (_Float16)v1.z; hv[7] = (_Float16)v1.w;
        *(half8*)&Bs[sl * 8] = hv;
    }

    // per-thread channel params (hh = 0/1 -> cc = hh*16 + n16)
    float rba[2], rbi[2], ral[2];
#pragma unroll
    for (int hh = 0; hh < 2; ++hh) {
        int e = ebase + hh * 16 + n16;
        rba[hh] = bap[e];
        rbi[hh] = bip[e];
        ral[hh] = sigf(gp[e]);
    }
    if (tid < 32) carry[tid] = 0.0f;

    // incremental recency weight: sc(s) = exp(3s/2047)
    float scb = __expf((float)(w * 16 + quad * 4) * (3.0f / 2047.0f));
    const float r1    = __expf(3.0f / 2047.0f);
    const float r2    = r1 * r1;
    const float r3    = r2 * r1;
    const float cs128 = __expf(128.0f * 3.0f / 2047.0f);

    // A-row for this lane: s_local = w*16 + n16 (= MFMA m index)
    const float* xbase = x + ((size_t)b * SEQ + (size_t)(w * 16 + n16)) * DIM + quad * 8;
    _Float16* cmbb = cmb + (size_t)b * SEQ * NCH + cg * 32 + n16;

    __syncthreads();

    // preload tile 0's A data (fp32)
    float4 xf[8];
#pragma unroll
    for (int ks = 0; ks < 4; ++ks) {
        xf[2 * ks]     = *(const float4*)(xbase + ks * 32);
        xf[2 * ks + 1] = *(const float4*)(xbase + ks * 32 + 4);
    }

    for (int t = 0; t < 16; ++t) {
        const int s0 = t * 128;

        // ---- convert prefetched fp32 -> fp16 A-frags ----
        half8 af[4];
#pragma unroll
        for (int ks = 0; ks < 4; ++ks) {
            float4 v0 = xf[2 * ks], v1 = xf[2 * ks + 1];
            half8 hv;
            hv[0] = (_Float16)v0.x; hv[1] = (_Float16)v0.y;
            hv[2] = (_Float16)v0.z; hv[3] = (_Float16)v0.w;
            hv[4] = (_Float16)v1.x; hv[5] = (_Float16)v1.y;
            hv[6] = (_Float16)v1.z; hv[7] = (_Float16)v1.w;
            af[ks] = hv;
        }

        // ---- MFMA: 4 n-tiles, K=128 ----
        f32x4 acc[4];
#pragma unroll
        for (int nt = 0; nt < 4; ++nt) acc[nt] = (f32x4){0.f, 0.f, 0.f, 0.f};
#pragma unroll
        for (int ks = 0; ks < 4; ++ks) {
            half8 a = af[ks];
#pragma unroll
            for (int nt = 0; nt < 4; ++nt) {
                half8 bb = *(const half8*)&Bs[(ks * 256 + nt * 64 + lane) * 8];
                acc[nt] = __builtin_amdgcn_mfma_f32_16x16x32_f16(a, bb, acc[nt], 0, 0, 0);
            }
        }

        // ---- prefetch next tile's A data (wraps at t=15; harmless) ----
        {
            int tn = (t + 1) & 15;
            const float* ab = xbase + (size_t)tn * 128 * DIM;
#pragma unroll
            for (int ks = 0; ks < 4; ++ks) {
                xf[2 * ks]     = *(const float4*)(ab + ks * 32);
                xf[2 * ks + 1] = *(const float4*)(ab + ks * 32 + 4);
            }
        }

        // ---- gates + 4-step affine compose (2 channels) ----
        float sc[4];
        if (p) { sc[0] = scb; sc[1] = scb * r1; sc[2] = scb * r2; sc[3] = scb * r3; }
        else   { sc[0] = sc[1] = sc[2] = sc[3] = 1.0f; }
        scb *= cs128;

        float a_s[2][4], u_s[2][4];
#pragma unroll
        for (int hh = 0; hh < 2; ++hh) {
            float A4 = 1.0f, U4 = 0.0f;
#pragma unroll
            for (int reg = 0; reg < 4; ++reg) {
                float pa = fmaf(acc[hh][reg],     sc[reg], rba[hh]);
                float pi = fmaf(acc[2 + hh][reg], sc[reg], rbi[hh]);
                float rst = sigf(pa);
                float ig  = sigf(pi);
                float a   = ral[hh] * exp2f(-rst * 1.5849625007211562f);  // alpha*3^-rst
                float u   = sqrtf(fmaxf(1.0f - a * a, 0.0f)) * ig * pi;
                a_s[hh][reg] = a; u_s[hh][reg] = u;
                A4 *= a;
                U4 = fmaf(a, U4, u);
            }
            seg[w * 4 + quad][hh * 16 + n16] = make_float2(A4, U4);
        }
        __syncthreads();

        // ---- serial inter-segment scan (32 segments, lane = channel) ----
        if (tid < 32) {
            float H = carry[tid];
#pragma unroll
            for (int ts = 0; ts < 32; ++ts) {
                float2 AU = seg[ts][tid];
                pref[ts][tid] = H;
                H = fmaf(AU.x, H, AU.y);
            }
            carry[tid] = H;
        }
        __syncthreads();

        // ---- replay + direct store (2B/lane, 16-lane = 32B segments) ----
#pragma unroll
        for (int hh = 0; hh < 2; ++hh) {
            float h = pref[w * 4 + quad][hh * 16 + n16];
            _Float16* dst = cmbb + (size_t)(s0 + w * 16 + quad * 4) * NCH + hh * 16;
#pragma unroll
            for (int reg = 0; reg < 4; ++reg) {
                h = fmaf(a_s[hh][reg], h, u_s[hh][reg]);
                dst[(size_t)reg * NCH] = (_Float16)h;
            }
        }
    }
}

// ---------------------------------------------------------------------------
// k3: round-3 structure VERBATIM (measured ~40 µs): 128-row tile, 64-wide K
//     pages, 32 MFMA/barrier, grid 512 = 2 blocks/CU.
// ---------------------------------------------------------------------------
__global__ __launch_bounds__(256, 2) void k3_mfma(
        const _Float16* __restrict__ cmb, const _Float16* __restrict__ Wfg,
        const float* __restrict__ bfv, float* __restrict__ out) {
    __shared__ _Float16 As[16 * 512];
    __shared__ _Float16 Bs[16 * 512];

    const int tid  = threadIdx.x;
    const int lane = tid & 63;
    const int w    = tid >> 6;
    const int row0 = blockIdx.x * 128;
    const int q    = lane >> 4;
    const int nn   = lane & 15;

    f32x4 acc[2][8];
#pragma unroll
    for (int rt = 0; rt < 2; ++rt)
#pragma unroll
        for (int ct = 0; ct < 8; ++ct)
            acc[rt][ct] = (f32x4){0.0f, 0.0f, 0.0f, 0.0f};

    for (int kb = 0; kb < 8; ++kb) {
        const int kc = kb * 64;
#pragma unroll
        for (int i = 0; i < 4; ++i) {
            int f = tid + i * 256;
            int r = f >> 3, k8 = f & 7;
            uint4 v = *(const uint4*)(cmb + (size_t)(row0 + r) * NCH + kc + k8 * 8);
            int rt = r >> 4, m = r & 15, ks = k8 >> 2, qq = k8 & 3;
            *(uint4*)&As[(((rt * 2 + ks) * 64) + qq * 16 + m) * 8] = v;
        }
#pragma unroll
        for (int i = 0; i < 4; ++i) {
            int f = tid + i * 256;
            uint4 v = *(const uint4*)(Wfg + (size_t)kb * 8192 + (size_t)f * 8);
            *(uint4*)&Bs[(size_t)f * 8] = v;
        }
        __syncthreads();

#pragma unroll
        for (int ks = 0; ks < 2; ++ks) {
            half8 a0 = *(const half8*)&As[(((w * 2 + 0) * 2 + ks) * 512) + lane * 8];
            half8 a1 = *(const half8*)&As[(((w * 2 + 1) * 2 + ks) * 512) + lane * 8];
#pragma unroll
            for (int ct = 0; ct < 8; ++ct) {
                half8 bb = *(const half8*)&Bs[((ks * 8 + ct) * 512) + lane * 8];
                acc[0][ct] = __builtin_amdgcn_mfma_f32_16x16x32_f16(a0, bb, acc[0][ct], 0, 0, 0);
                acc[1][ct] = __builtin_amdgcn_mfma_f32_16x16x32_f16(a1, bb, acc[1][ct], 0, 0, 0);
            }
        }
        __syncthreads();
    }

#pragma unroll
    for (int rt = 0; rt < 2; ++rt) {
        int rbase = row0 + w * 32 + rt * 16 + q * 4;
#pragma unroll
        for (int ct = 0; ct < 8; ++ct) {
            int col = ct * 16 + nn;
            float bias = bfv[col];
#pragma unroll
            for (int reg = 0; reg < 4; ++reg)
                out[(size_t)(rbase + reg) * DIM + col] = acc[rt][ct][reg] + bias;
        }
    }
}

// ---------------------------------------------------------------------------
extern "C" void kernel_launch(void* const* d_in, const int* in_sizes, int n_in,
                              void* d_out, int out_size, void* d_ws, size_t ws_size,
                              hipStream_t stream) {
    if (ws_size < WS_NEEDED) return;

    const float* x    = (const float*)d_in[0];
    const float* Wa_u = (const float*)d_in[1];
    const float* ba_u = (const float*)d_in[2];
    const float* Wi_u = (const float*)d_in[3];
    const float* bi_u = (const float*)d_in[4];
    const float* g_u  = (const float*)d_in[5];
    const float* Wa_w = (const float*)d_in[6];
    const float* ba_w = (const float*)d_in[7];
    const float* Wi_w = (const float*)d_in[8];
    const float* bi_w = (const float*)d_in[9];
    const float* g_w  = (const float*)d_in[10];
    const float* Wf   = (const float*)d_in[11];
    const float* bfv  = (const float*)d_in[12];
    float* out = (float*)d_out;

    char* ws = (char*)d_ws;
    _Float16* cmb = (_Float16*)ws;
    _Float16* Wfg = (_Float16*)(ws + WFG_OFF);

    hipLaunchKernelGGL(k0_wfg, dim3(32), dim3(256), 0, stream, Wf, Wfg);
    hipLaunchKernelGGL(kfused, dim3(32, 16), dim3(512), 0, stream,
                       x, Wa_u, ba_u, Wi_u, bi_u, g_u,
                       Wa_w, ba_w, Wi_w, bi_w, g_w, cmb);
    hipLaunchKernelGGL(k3_mfma, dim3(512), dim3(256), 0, stream,
                       cmb, Wfg, bfv, out);
}

// Round 9
// 198.777 us; speedup vs baseline: 1.2166x; 1.0310x over previous
//
#include <hip/hip_runtime.h>
#include <hip/hip_fp16.h>
#include <cstddef>
#include <cstdint>

#define DIM 128
#define SEQ 2048
#define NB 32
#define NCH 512
#define NROWS (NB * SEQ)          // 65536

typedef _Float16 half8 __attribute__((ext_vector_type(8)));
typedef float    f32x4 __attribute__((ext_vector_type(4)));

// ws layout: cmb fp16 [NROWS][NCH] | Wfg fp16 frag-linear [65536]
#define CMB_BYTES ((size_t)NROWS * NCH * 2)       // 67,108,864
#define WFG_OFF   CMB_BYTES
#define WFG_BYTES ((size_t)NCH * DIM * 2)         // 131,072
#define WS_NEEDED (WFG_OFF + WFG_BYTES)           // ~64.1 MB (proven available)

__device__ __forceinline__ float sigf(float v) {
    return 1.0f / (1.0f + __expf(-v));
}

// ---------------------------------------------------------------------------
// k0: Wfg = Wf (fp16) pre-swizzled into MFMA B-fragment linear layout.
// ---------------------------------------------------------------------------
__global__ void k0_wfg(const float* __restrict__ Wf, _Float16* __restrict__ Wfg) {
    int t = blockIdx.x * 256 + threadIdx.x;       // 8192 threads x 8 elems
#pragma unroll
    for (int i = 0; i < 8; ++i) {
        int o = t * 8 + i;                         // 65536 total
        int j    = o & 7;
        int lane = (o >> 3) & 63;
        int q    = lane >> 4, n16 = lane & 15;
        int ct   = (o >> 9) & 7;
        int ks   = (o >> 12) & 1;
        int kb   = o >> 13;
        int k = kb * 64 + ks * 32 + q * 8 + j;
        int n = ct * 16 + n16;
        Wfg[o] = (_Float16)Wf[n * NCH + k];
    }
}

// ---------------------------------------------------------------------------
// kfused v8: R8 structure (32ch/block, 512 thr, grid 32x16) with an EXPLICIT
//   A-fragment software pipeline: xf loads for tile t+1 issue right after
//   tile t's MFMAs; fp32->fp16 conversion happens in the scan window
//   (barrier-1 .. barrier-2), pinned with sched_barrier(0), so af_next is
//   ready in registers when the next tile starts. 2 barriers/tile.
// ---------------------------------------------------------------------------
__global__ __launch_bounds__(512, 4) void kfused(
        const float* __restrict__ x,
        const float* __restrict__ Wa_u, const float* __restrict__ ba_u,
        const float* __restrict__ Wi_u, const float* __restrict__ bi_u,
        const float* __restrict__ g_u,
        const float* __restrict__ Wa_w, const float* __restrict__ ba_w,
        const float* __restrict__ Wi_w, const float* __restrict__ bi_w,
        const float* __restrict__ g_w,
        _Float16* __restrict__ cmb) {
    __shared__ _Float16 Bs[8192];        // [ks(4)][nt(4)][lane(64)][8] = 16 KB
    __shared__ float2   seg[32][33];     // (A,U) per (segment, channel)
    __shared__ float    pref[32][33];    // incoming h per (segment, channel)
    __shared__ float    carry[32];

    const int tid  = threadIdx.x;
    const int lane = tid & 63;
    const int w    = tid >> 6;           // wave 0..7 = m-tile (16 s each)
    const int quad = lane >> 4;
    const int n16  = lane & 15;

    const int b  = blockIdx.x;           // 0..31
    const int cg = blockIdx.y;           // 0..15
    const int p  = cg >> 3;              // path
    const int ebase = (cg & 7) * 32;     // 32 channels per block

    const float* Wa  = p ? Wa_w : Wa_u;
    const float* Wi  = p ? Wi_w : Wi_u;
    const float* bap = p ? ba_w : ba_u;
    const float* bip = p ? bi_w : bi_u;
    const float* gp  = p ? g_w  : g_u;

    // ---- stage Bs once: slot sl = ks*256 + nt*64 + l (1024 slots, 2/thread)
    for (int sl = tid; sl < 1024; sl += 512) {
        int l  = sl & 63;
        int nt = (sl >> 6) & 3;
        int ks = sl >> 8;
        int qq = l >> 4, nn = l & 15;
        int e = ebase + (nt & 1) * 16 + nn;
        const float* Wp = (nt >> 1) ? Wi : Wa;
        const float* src = Wp + (size_t)e * DIM + ks * 32 + qq * 8;
        float4 v0 = *(const float4*)src;
        float4 v1 = *(const float4*)(src + 4);
        half8 hv;
        hv[0] = (_Float16)v0.x; hv[1] = (_Float16)v0.y;
        hv[2] = (_Float16)v0.z; hv[3] = (_Float16)v0.w;
        hv[4] = (_Float16)v1.x; hv[5] = (_Float16)v1.y;
        hv[6] = (_Float16)v1.z; hv[7] = (_Float16)v1.w;
        *(half8*)&Bs[sl * 8] = hv;
    }

    // per-thread channel params (hh = 0/1 -> cc = hh*16 + n16)
    float rba[2], rbi[2], ral[2];
#pragma unroll
    for (int hh = 0; hh < 2; ++hh) {
        int e = ebase + hh * 16 + n16;
        rba[hh] = bap[e];
        rbi[hh] = bip[e];
        ral[hh] = sigf(gp[e]);
    }
    if (tid < 32) carry[tid] = 0.0f;

    // incremental recency weight: sc(s) = exp(3s/2047)
    float scb = __expf((float)(w * 16 + quad * 4) * (3.0f / 2047.0f));
    const float r1    = __expf(3.0f / 2047.0f);
    const float r2    = r1 * r1;
    const float r3    = r2 * r1;
    const float cs128 = __expf(128.0f * 3.0f / 2047.0f);

    // A-row for this lane: s_local = w*16 + n16 (= MFMA m index)
    const float* xbase = x + ((size_t)b * SEQ + (size_t)(w * 16 + n16)) * DIM + quad * 8;
    _Float16* cmbb = cmb + (size_t)b * SEQ * NCH + cg * 32 + n16;

    __syncthreads();

    // ---- prologue: load + convert tile 0's A-frags ----
    half8 af[4];
    {
        float4 xf0[8];
#pragma unroll
        for (int ks = 0; ks < 4; ++ks) {
            xf0[2 * ks]     = *(const float4*)(xbase + ks * 32);
            xf0[2 * ks + 1] = *(const float4*)(xbase + ks * 32 + 4);
        }
#pragma unroll
        for (int ks = 0; ks < 4; ++ks) {
            float4 v0 = xf0[2 * ks], v1 = xf0[2 * ks + 1];
            half8 hv;
            hv[0] = (_Float16)v0.x; hv[1] = (_Float16)v0.y;
            hv[2] = (_Float16)v0.z; hv[3] = (_Float16)v0.w;
            hv[4] = (_Float16)v1.x; hv[5] = (_Float16)v1.y;
            hv[6] = (_Float16)v1.z; hv[7] = (_Float16)v1.w;
            af[ks] = hv;
        }
    }

    for (int t = 0; t < 16; ++t) {
        const int s0 = t * 128;

        // ---- MFMA: 4 n-tiles, K=128 (uses af, ready from last tile) ----
        f32x4 acc[4];
#pragma unroll
        for (int nt = 0; nt < 4; ++nt) acc[nt] = (f32x4){0.f, 0.f, 0.f, 0.f};
#pragma unroll
        for (int ks = 0; ks < 4; ++ks) {
            half8 a = af[ks];
#pragma unroll
            for (int nt = 0; nt < 4; ++nt) {
                half8 bb = *(const half8*)&Bs[(ks * 256 + nt * 64 + lane) * 8];
                acc[nt] = __builtin_amdgcn_mfma_f32_16x16x32_f16(a, bb, acc[nt], 0, 0, 0);
            }
        }

        // ---- issue next tile's A loads NOW (fly across gates/compose) ----
        float4 xf[8];
        {
            int tn = (t + 1) & 15;
            const float* ab = xbase + (size_t)tn * 128 * DIM;
#pragma unroll
            for (int ks = 0; ks < 4; ++ks) {
                xf[2 * ks]     = *(const float4*)(ab + ks * 32);
                xf[2 * ks + 1] = *(const float4*)(ab + ks * 32 + 4);
            }
        }

        // ---- gates + 4-step affine compose (2 channels) ----
        float sc[4];
        if (p) { sc[0] = scb; sc[1] = scb * r1; sc[2] = scb * r2; sc[3] = scb * r3; }
        else   { sc[0] = sc[1] = sc[2] = sc[3] = 1.0f; }
        scb *= cs128;

        float a_s[2][4], u_s[2][4];
#pragma unroll
        for (int hh = 0; hh < 2; ++hh) {
            float A4 = 1.0f, U4 = 0.0f;
#pragma unroll
            for (int reg = 0; reg < 4; ++reg) {
                float pa = fmaf(acc[hh][reg],     sc[reg], rba[hh]);
                float pi = fmaf(acc[2 + hh][reg], sc[reg], rbi[hh]);
                float rst = sigf(pa);
                float ig  = sigf(pi);
                float a   = ral[hh] * exp2f(-rst * 1.5849625007211562f);  // alpha*3^-rst
                float u   = sqrtf(fmaxf(1.0f - a * a, 0.0f)) * ig * pi;
                a_s[hh][reg] = a; u_s[hh][reg] = u;
                A4 *= a;
                U4 = fmaf(a, U4, u);
            }
            seg[w * 4 + quad][hh * 16 + n16] = make_float2(A4, U4);
        }
        __syncthreads();   // barrier 1: seg visible

        // ---- scan window: wave-0 lanes scan; everyone converts xf -> af ----
        if (tid < 32) {
            float H = carry[tid];
#pragma unroll
            for (int ts = 0; ts < 32; ++ts) {
                float2 AU = seg[ts][tid];
                pref[ts][tid] = H;
                H = fmaf(AU.x, H, AU.y);
            }
            carry[tid] = H;
        }
        // convert next tile's A data in the otherwise-idle scan window
#pragma unroll
        for (int ks = 0; ks < 4; ++ks) {
            float4 v0 = xf[2 * ks], v1 = xf[2 * ks + 1];
            half8 hv;
            hv[0] = (_Float16)v0.x; hv[1] = (_Float16)v0.y;
            hv[2] = (_Float16)v0.z; hv[3] = (_Float16)v0.w;
            hv[4] = (_Float16)v1.x; hv[5] = (_Float16)v1.y;
            hv[6] = (_Float16)v1.z; hv[7] = (_Float16)v1.w;
            af[ks] = hv;
        }
        __builtin_amdgcn_sched_barrier(0);   // pin loads+convert here
        __syncthreads();   // barrier 2: pref/carry visible

        // ---- replay + direct store (2B/lane, 16-lane = 32B segments) ----
#pragma unroll
        for (int hh = 0; hh < 2; ++hh) {
            float h = pref[w * 4 + quad][hh * 16 + n16];
            _Float16* dst = cmbb + (size_t)(s0 + w * 16 + quad * 4) * NCH + hh * 16;
#pragma unroll
            for (int reg = 0; reg < 4; ++reg) {
                h = fmaf(a_s[hh][reg], h, u_s[hh][reg]);
                dst[(size_t)reg * NCH] = (_Float16)h;
            }
        }
    }
}

// ---------------------------------------------------------------------------
// k3: round-3 structure VERBATIM: 128-row tile, 64-wide K pages,
//     32 MFMA/barrier, grid 512 = 2 blocks/CU.
// ---------------------------------------------------------------------------
__global__ __launch_bounds__(256, 2) void k3_mfma(
        const _Float16* __restrict__ cmb, const _Float16* __restrict__ Wfg,
        const float* __restrict__ bfv, float* __restrict__ out) {
    __shared__ _Float16 As[16 * 512];
    __shared__ _Float16 Bs[16 * 512];

    const int tid  = threadIdx.x;
    const int lane = tid & 63;
    const int w    = tid >> 6;
    const int row0 = blockIdx.x * 128;
    const int q    = lane >> 4;
    const int nn   = lane & 15;

    f32x4 acc[2][8];
#pragma unroll
    for (int rt = 0; rt < 2; ++rt)
#pragma unroll
        for (int ct = 0; ct < 8; ++ct)
            acc[rt][ct] = (f32x4){0.0f, 0.0f, 0.0f, 0.0f};

    for (int kb = 0; kb < 8; ++kb) {
        const int kc = kb * 64;
#pragma unroll
        for (int i = 0; i < 4; ++i) {
            int f = tid + i * 256;
            int r = f >> 3, k8 = f & 7;
            uint4 v = *(const uint4*)(cmb + (size_t)(row0 + r) * NCH + kc + k8 * 8);
            int rt = r >> 4, m = r & 15, ks = k8 >> 2, qq = k8 & 3;
            *(uint4*)&As[(((rt * 2 + ks) * 64) + qq * 16 + m) * 8] = v;
        }
#pragma unroll
        for (int i = 0; i < 4; ++i) {
            int f = tid + i * 256;
            uint4 v = *(const uint4*)(Wfg + (size_t)kb * 8192 + (size_t)f * 8);
            *(uint4*)&Bs[(size_t)f * 8] = v;
        }
        __syncthreads();

#pragma unroll
        for (int ks = 0; ks < 2; ++ks) {
            half8 a0 = *(const half8*)&As[(((w * 2 + 0) * 2 + ks) * 512) + lane * 8];
            half8 a1 = *(const half8*)&As[(((w * 2 + 1) * 2 + ks) * 512) + lane * 8];
#pragma unroll
            for (int ct = 0; ct < 8; ++ct) {
                half8 bb = *(const half8*)&Bs[((ks * 8 + ct) * 512) + lane * 8];
                acc[0][ct] = __builtin_amdgcn_mfma_f32_16x16x32_f16(a0, bb, acc[0][ct], 0, 0, 0);
                acc[1][ct] = __builtin_amdgcn_mfma_f32_16x16x32_f16(a1, bb, acc[1][ct], 0, 0, 0);
            }
        }
        __syncthreads();
    }

#pragma unroll
    for (int rt = 0; rt < 2; ++rt) {
        int rbase = row0 + w * 32 + rt * 16 + q * 4;
#pragma unroll
        for (int ct = 0; ct < 8; ++ct) {
            int col = ct * 16 + nn;
            float bias = bfv[col];
#pragma unroll
            for (int reg = 0; reg < 4; ++reg)
                out[(size_t)(rbase + reg) * DIM + col] = acc[rt][ct][reg] + bias;
        }
    }
}

// ---------------------------------------------------------------------------
extern "C" void kernel_launch(void* const* d_in, const int* in_sizes, int n_in,
                              void* d_out, int out_size, void* d_ws, size_t ws_size,
                              hipStream_t stream) {
    if (ws_size < WS_NEEDED) return;

    const float* x    = (const float*)d_in[0];
    const float* Wa_u = (const float*)d_in[1];
    const float* ba_u = (const float*)d_in[2];
    const float* Wi_u = (const float*)d_in[3];
    const float* bi_u = (const float*)d_in[4];
    const float* g_u  = (const float*)d_in[5];
    const float* Wa_w = (const float*)d_in[6];
    const float* ba_w = (const float*)d_in[7];
    const float* Wi_w = (const float*)d_in[8];
    const float* bi_w = (const float*)d_in[9];
    const float* g_w  = (const float*)d_in[10];
    const float* Wf   = (const float*)d_in[11];
    const float* bfv  = (const float*)d_in[12];
    float* out = (float*)d_out;

    char* ws = (char*)d_ws;
    _Float16* cmb = (_Float16*)ws;
    _Float16* Wfg = (_Float16*)(ws + WFG_OFF);

    hipLaunchKernelGGL(k0_wfg, dim3(32), dim3(256), 0, stream, Wf, Wfg);
    hipLaunchKernelGGL(kfused, dim3(32, 16), dim3(512), 0, stream,
                       x, Wa_u, ba_u, Wi_u, bi_u, g_u,
                       Wa_w, ba_w, Wi_w, bi_w, g_w, cmb);
    hipLaunchKernelGGL(k3_mfma, dim3(512), dim3(256), 0, stream,
                       cmb, Wfg, bfv, out);
}